// Round 1
// baseline (2538.547 us; speedup 1.0000x reference)
//
#include <hip/hip_runtime.h>
#include <hip/hip_bf16.h>

#define INF_F 1000000000000.0f

typedef __attribute__((ext_vector_type(8))) short bfrag8;
typedef __attribute__((ext_vector_type(4))) float facc4;

__device__ __forceinline__ float sigf(float x){ return 1.0f/(1.0f + expf(-x)); }

// out-region offsets (floats)
#define OFF_LOG 0ull
#define OFF_A   32819200ull
#define OFF_C   33228800ull
#define OFF_E   33638400ull

// ---------------- init ----------------
__global__ __launch_bounds__(256) void k_init(const float* __restrict__ init_s,
    float* __restrict__ hbuf, float* __restrict__ c0, float* __restrict__ ctxb,
    float* __restrict__ cov) {
  int i = blockIdx.x*256 + threadIdx.x;
  if (i < 32*512) { float v = init_s[i]; hbuf[i]=v; c0[i]=v; ctxb[i]=0.0f; }
  if (i < 32*400) cov[i] = 0.0f;
}

// ---------------- b_combo = W_ih@b_red + b_ih + b_hh ----------------
__global__ __launch_bounds__(256) void k_bcombo(const float* __restrict__ W_ih,
    const float* __restrict__ b_red, const float* __restrict__ b_ih,
    const float* __restrict__ b_hh, float* __restrict__ bcomb) {
  int j = blockIdx.x*256 + threadIdx.x;
  if (j >= 2048) return;
  float acc = b_ih[j] + b_hh[j];
  for (int m=0;m<300;m++) acc += W_ih[j*300+m]*b_red[m];
  bcomb[j] = acc;
}

// ---------------- Wct[2048][812] = W_ih[2048x300] @ W_red[300x812] ----------------
__global__ __launch_bounds__(256) void k_wcombo(const float* __restrict__ W_ih,
    const float* __restrict__ W_red, float* __restrict__ Wct) {
  __shared__ float As[16][68];
  __shared__ float Bs[16][68];
  int tid = threadIdx.x;
  int m0 = blockIdx.y*64, n0 = blockIdx.x*64;
  int rl = tid>>2, kq = (tid&3)*4;
  int kl = tid>>4, c4 = (tid&15)*4;
  int tx = tid&15, ty = tid>>4;
  float acc[4][4]={};
  for (int kk=0;kk<300;kk+=16){
    #pragma unroll
    for (int q=0;q<4;q++){
      int kg = kk+kq+q;
      As[kq+q][rl] = (kg<300) ? W_ih[(size_t)(m0+rl)*300 + kg] : 0.0f;
    }
    #pragma unroll
    for (int q=0;q<4;q++){
      int c = n0 + c4 + q;
      Bs[kl][c4+q] = (kk+kl<300 && c<812) ? W_red[(size_t)(kk+kl)*812 + c] : 0.0f;
    }
    __syncthreads();
    #pragma unroll
    for (int k=0;k<16;k++){
      const float* ap=&As[k][ty*4]; const float* bp=&Bs[k][tx*4];
      #pragma unroll
      for (int i=0;i<4;i++)
        #pragma unroll
        for (int j=0;j<4;j++) acc[i][j] += ap[i]*bp[j];
    }
    __syncthreads();
  }
  #pragma unroll
  for (int i=0;i<4;i++)
    #pragma unroll
    for (int j=0;j<4;j++){
      int row = m0+ty*4+i, col = n0+tx*4+j;
      if (col<812) Wct[(size_t)row*812 + col] = acc[i][j];
    }
}

// ---------------- G_emb[1024][2048] = emb[1024x300] @ Wct[:,0:300]^T + b_combo --------
__global__ __launch_bounds__(256) void k_gemb(const float* __restrict__ trg,
    const float* __restrict__ Wct, const float* __restrict__ bcomb,
    float* __restrict__ Gemb) {
  __shared__ float As[16][68];
  __shared__ float Bs[16][68];
  int tid = threadIdx.x;
  int m0 = blockIdx.y*64, n0 = blockIdx.x*64;
  int rl = tid>>2, kq = (tid&3)*4;
  int tx = tid&15, ty = tid>>4;
  float acc[4][4]={};
  int r = m0 + rl;
  const float* arow = trg + (size_t)(r&31)*9600 + (size_t)(r>>5)*300;
  for (int kk=0;kk<300;kk+=16){
    #pragma unroll
    for (int q=0;q<4;q++){
      int kg = kk+kq+q;
      As[kq+q][rl] = (kg<300) ? arow[kg] : 0.0f;
      Bs[kq+q][rl] = (kg<300) ? Wct[(size_t)(n0+rl)*812 + kg] : 0.0f;
    }
    __syncthreads();
    #pragma unroll
    for (int k=0;k<16;k++){
      const float* ap=&As[k][ty*4]; const float* bp=&Bs[k][tx*4];
      #pragma unroll
      for (int i=0;i<4;i++)
        #pragma unroll
        for (int j=0;j<4;j++) acc[i][j] += ap[i]*bp[j];
    }
    __syncthreads();
  }
  #pragma unroll
  for (int i=0;i<4;i++)
    #pragma unroll
    for (int j=0;j<4;j++){
      int rr = m0+ty*4+i, col = n0+tx*4+j;
      Gemb[(size_t)rr*2048 + col] = acc[i][j] + bcomb[col];
    }
}

// ---------------- Wg[1024][2048]: k<512 -> Wct[:,300+k]^T ; k>=512 -> W_hh^T ----------
__global__ __launch_bounds__(256) void k_wgpack(const float* __restrict__ Wct,
    const float* __restrict__ W_hh, float* __restrict__ Wg) {
  int idx = blockIdx.x*256 + threadIdx.x;
  if (idx >= 1024*2048) return;
  int k = idx >> 11, j = idx & 2047;
  Wg[idx] = (k < 512) ? Wct[(size_t)j*812 + 300 + k] : W_hh[(size_t)j*512 + (k-512)];
}

// ---------------- memories = enc @ W_enc^T + b_enc (dual layout) ----------------
__global__ __launch_bounds__(256) void k_memories(const float* __restrict__ A,
    const float* __restrict__ Bw, const float* __restrict__ bias,
    float* __restrict__ mem, float* __restrict__ memT) {
  __shared__ float As[16][68];
  __shared__ float Bs[16][68];
  int tid = threadIdx.x;
  int m0 = blockIdx.y*64, n0 = blockIdx.x*64;
  int rl = tid>>2, kq = (tid&3)*4;
  int tx = tid&15, ty = tid>>4;
  float acc[4][4]={};
  for (int kk=0;kk<512;kk+=16){
    float4 av = *(const float4*)(A  + (size_t)(m0+rl)*512 + kk+kq);
    float4 bv = *(const float4*)(Bw + (size_t)(n0+rl)*512 + kk+kq);
    As[kq+0][rl]=av.x; As[kq+1][rl]=av.y; As[kq+2][rl]=av.z; As[kq+3][rl]=av.w;
    Bs[kq+0][rl]=bv.x; Bs[kq+1][rl]=bv.y; Bs[kq+2][rl]=bv.z; Bs[kq+3][rl]=bv.w;
    __syncthreads();
    #pragma unroll
    for (int k=0;k<16;k++){
      const float* ap=&As[k][ty*4]; const float* bp=&Bs[k][tx*4];
      #pragma unroll
      for (int i=0;i<4;i++)
        #pragma unroll
        for (int j=0;j<4;j++) acc[i][j] += ap[i]*bp[j];
    }
    __syncthreads();
  }
  #pragma unroll
  for (int i=0;i<4;i++){
    int n = m0+ty*4+i;
    int bb = n/400, s = n - bb*400;
    #pragma unroll
    for (int j=0;j<4;j++){
      int h = n0+tx*4+j;
      float v = acc[i][j] + bias[h];
      mem[(size_t)n*512 + h] = v;
      memT[((size_t)bb*512 + h)*400 + s] = v;
    }
  }
}

// ---------------- W_log -> bf16 ----------------
__global__ __launch_bounds__(256) void k_wlogconv(const float* __restrict__ W_log,
    __hip_bfloat16* __restrict__ wlb) {
  int i4 = blockIdx.x*256 + threadIdx.x;
  if (i4 >= 32000*512/4) return;
  const float4 v = *(const float4*)(W_log + (size_t)i4*4);
  size_t o = (size_t)i4*4;
  wlb[o+0] = __float2bfloat16(v.x); wlb[o+1] = __float2bfloat16(v.y);
  wlb[o+2] = __float2bfloat16(v.z); wlb[o+3] = __float2bfloat16(v.w);
}

// ---------------- per-step: gates partial GEMM ----------------
// grid (ks=8, rc=16); partial[ks][b][row] = sum_{k in ks chunk} yh[b][k]*Wg[k][row]
__global__ __launch_bounds__(256) void k_gates(const float* __restrict__ ctxb,
    const float* __restrict__ hbuf, const float* __restrict__ Wg,
    float* __restrict__ partials) {
  __shared__ float yh_s[128][32];
  int ks = blockIdx.x;
  int rc = blockIdx.y;
  int tid = threadIdx.x;
  const float* side = (ks < 4) ? ctxb : hbuf;
  int kbase = (ks & 3) * 128;
  {
    int b_l = tid >> 3, kq0 = (tid & 7) * 16;
    const float* src = side + (size_t)b_l*512 + kbase + kq0;
    #pragma unroll
    for (int q=0;q<16;q+=4){
      float4 v = *(const float4*)(src + q);
      yh_s[kq0+q+0][b_l]=v.x; yh_s[kq0+q+1][b_l]=v.y;
      yh_s[kq0+q+2][b_l]=v.z; yh_s[kq0+q+3][b_l]=v.w;
    }
  }
  __syncthreads();
  int tr = tid & 31, bg = tid >> 5;
  int row0 = rc*128 + tr*4;
  float acc[4][4] = {};
  const float* wp = Wg + (size_t)(ks*128)*2048 + row0;
  #pragma unroll 4
  for (int k=0;k<128;k++){
    float4 w = *(const float4*)(wp + (size_t)k*2048);
    float4 y = *(const float4*)&yh_s[k][bg*4];
    acc[0][0]+=w.x*y.x; acc[0][1]+=w.x*y.y; acc[0][2]+=w.x*y.z; acc[0][3]+=w.x*y.w;
    acc[1][0]+=w.y*y.x; acc[1][1]+=w.y*y.y; acc[1][2]+=w.y*y.z; acc[1][3]+=w.y*y.w;
    acc[2][0]+=w.z*y.x; acc[2][1]+=w.z*y.y; acc[2][2]+=w.z*y.z; acc[2][3]+=w.z*y.w;
    acc[3][0]+=w.w*y.x; acc[3][1]+=w.w*y.y; acc[3][2]+=w.w*y.z; acc[3][3]+=w.w*y.w;
  }
  #pragma unroll
  for (int j=0;j<4;j++){
    float4 o; o.x=acc[0][j]; o.y=acc[1][j]; o.z=acc[2][j]; o.w=acc[3][j];
    *(float4*)(partials + (size_t)(ks*32 + bg*4 + j)*2048 + row0) = o;
  }
}

// ---------------- per-step: reduce + LSTM + energy ----------------
// grid (sc=2, b=32)
__global__ __launch_bounds__(256) void k_lstm_energy(const float* __restrict__ partials,
    const float* __restrict__ Gemb, const float* __restrict__ c_in, float* __restrict__ c_out,
    float* __restrict__ hbuf, float* __restrict__ hall, const float* __restrict__ memT,
    const int* __restrict__ emask, float* __restrict__ out, int t) {
  __shared__ float gl[2048];
  __shared__ float hl[512];
  int sc = blockIdx.x, b = blockIdx.y, tid = threadIdx.x;
  int r = t*32 + b;
  for (int row=tid; row<2048; row+=256){
    float v = Gemb[(size_t)r*2048 + row];
    #pragma unroll
    for (int ks=0;ks<8;ks++) v += partials[(size_t)(ks*32+b)*2048 + row];
    gl[row] = v;
  }
  __syncthreads();
  for (int j=tid; j<512; j+=256){
    float iv=gl[j], fv=gl[512+j], gv=gl[1024+j], ov=gl[1536+j];
    float cp = c_in[b*512+j];
    float cn = sigf(fv)*cp + sigf(iv)*tanhf(gv);
    float hn = sigf(ov)*tanhf(cn);
    hl[j]=hn;
    if (sc==0){
      c_out[b*512+j]=cn;
      hbuf[b*512+j]=hn;
      hall[(size_t)r*512+j]=hn;
    }
  }
  __syncthreads();
  if (tid < 200){
    int s = sc*200 + tid;
    float acc=0.0f;
    const float* mp = memT + (size_t)b*512*400 + s;
    #pragma unroll 8
    for (int h=0;h<512;h++) acc += hl[h]*mp[(size_t)h*400];
    float e = (emask[b*400+s]==0) ? -INF_F : acc;
    out[OFF_E + (size_t)r*400 + s] = e;
  }
}

// ---------------- per-step: softmax + ctx + attn/cov outputs ----------------
// grid (hc=2, b=32)
__global__ __launch_bounds__(256) void k_ctx(float* __restrict__ out,
    const float* __restrict__ mem, float* __restrict__ ctxb, float* __restrict__ ctxa,
    float* __restrict__ cov, int t) {
  __shared__ float p[400];
  __shared__ float red[256];
  int hc = blockIdx.x, b = blockIdx.y, tid = threadIdx.x;
  int r = t*32 + b;
  for (int s=tid;s<400;s+=256) p[s] = out[OFF_E + (size_t)r*400 + s];
  __syncthreads();
  float lm = -3.4e38f;
  for (int s=tid;s<400;s+=256) lm = fmaxf(lm, p[s]);
  red[tid]=lm; __syncthreads();
  for (int o=128;o>0;o>>=1){ if(tid<o) red[tid]=fmaxf(red[tid],red[tid+o]); __syncthreads(); }
  float m = red[0]; __syncthreads();
  float ls = 0.0f;
  for (int s=tid;s<400;s+=256){ float pv = expf(p[s]-m); p[s]=pv; ls+=pv; }
  red[tid]=ls; __syncthreads();
  for (int o=128;o>0;o>>=1){ if(tid<o) red[tid]+=red[tid+o]; __syncthreads(); }
  float inv = 1.0f/red[0];
  int h = hc*256 + tid;
  float acc=0.0f;
  const float* mp = mem + (size_t)b*400*512 + h;
  for (int s=0;s<400;s++) acc += p[s]*mp[(size_t)s*512];
  acc *= inv;
  ctxb[b*512+h]=acc;
  ctxa[(size_t)r*512+h]=acc;
  if (hc==0){
    for (int s=tid;s<400;s+=256){
      float a = p[s]*inv;
      out[OFF_A + (size_t)r*400 + s] = a;
      float cv = cov[b*400+s];
      out[OFF_C + (size_t)r*400 + s] = cv;
      cov[b*400+s] = cv + a;
    }
  }
}

// ---------------- logit_in = tanh([h_all|ctx_all]@W_cat^T + b_cat) -> bf16 ----------
__global__ __launch_bounds__(256) void k_logitin(const float* __restrict__ hall,
    const float* __restrict__ ctxa, const float* __restrict__ W_cat,
    const float* __restrict__ b_cat, __hip_bfloat16* __restrict__ lib) {
  __shared__ float As[16][68];
  __shared__ float Bs[16][68];
  int tid = threadIdx.x;
  int m0 = blockIdx.y*64, n0 = blockIdx.x*64;
  int rl = tid>>2, kq = (tid&3)*4;
  int tx = tid&15, ty = tid>>4;
  float acc[4][4]={};
  for (int kk=0;kk<1024;kk+=16){
    int kg = kk+kq;
    const float* asrc = (kg<512) ? (hall + (size_t)(m0+rl)*512 + kg)
                                 : (ctxa + (size_t)(m0+rl)*512 + kg - 512);
    float4 av = *(const float4*)asrc;
    float4 bv = *(const float4*)(W_cat + (size_t)(n0+rl)*1024 + kg);
    As[kq+0][rl]=av.x; As[kq+1][rl]=av.y; As[kq+2][rl]=av.z; As[kq+3][rl]=av.w;
    Bs[kq+0][rl]=bv.x; Bs[kq+1][rl]=bv.y; Bs[kq+2][rl]=bv.z; Bs[kq+3][rl]=bv.w;
    __syncthreads();
    #pragma unroll
    for (int k=0;k<16;k++){
      const float* ap=&As[k][ty*4]; const float* bp=&Bs[k][tx*4];
      #pragma unroll
      for (int i=0;i<4;i++)
        #pragma unroll
        for (int j=0;j<4;j++) acc[i][j] += ap[i]*bp[j];
    }
    __syncthreads();
  }
  #pragma unroll
  for (int i=0;i<4;i++)
    #pragma unroll
    for (int j=0;j<4;j++){
      int rr = m0+ty*4+i, col = n0+tx*4+j;
      float v = tanhf(acc[i][j] + b_cat[col]);
      lib[(size_t)rr*512 + col] = __float2bfloat16(v);
    }
}

// ---------------- logits = logit_in @ W_log^T + b_log (bf16 MFMA) ----------------
__global__ __launch_bounds__(256) void k_logits(const __hip_bfloat16* __restrict__ Ab,
    const __hip_bfloat16* __restrict__ Wb, const float* __restrict__ b_log,
    float* __restrict__ out) {
  int lane = threadIdx.x & 63, w = threadIdx.x >> 6;
  int wr = w >> 1, wc = w & 1;
  int m0 = blockIdx.y*64 + wr*32;
  int n0 = blockIdx.x*64 + wc*32;
  facc4 acc[2][2] = {{{0.f,0.f,0.f,0.f},{0.f,0.f,0.f,0.f}},
                     {{0.f,0.f,0.f,0.f},{0.f,0.f,0.f,0.f}}};
  const short* A = (const short*)Ab;
  const short* W = (const short*)Wb;
  int lr = lane & 15, lk = (lane >> 4) * 8;
  for (int k0 = 0; k0 < 512; k0 += 32) {
    bfrag8 a0 = *(const bfrag8*)(A + (size_t)(m0 + lr)*512      + k0 + lk);
    bfrag8 a1 = *(const bfrag8*)(A + (size_t)(m0 + 16 + lr)*512 + k0 + lk);
    bfrag8 b0 = *(const bfrag8*)(W + (size_t)(n0 + lr)*512      + k0 + lk);
    bfrag8 b1 = *(const bfrag8*)(W + (size_t)(n0 + 16 + lr)*512 + k0 + lk);
    acc[0][0] = __builtin_amdgcn_mfma_f32_16x16x32_bf16(a0, b0, acc[0][0], 0,0,0);
    acc[0][1] = __builtin_amdgcn_mfma_f32_16x16x32_bf16(a0, b1, acc[0][1], 0,0,0);
    acc[1][0] = __builtin_amdgcn_mfma_f32_16x16x32_bf16(a1, b0, acc[1][0], 0,0,0);
    acc[1][1] = __builtin_amdgcn_mfma_f32_16x16x32_bf16(a1, b1, acc[1][1], 0,0,0);
  }
  int orow = (lane >> 4) * 4;
  #pragma unroll
  for (int mi=0; mi<2; mi++)
    #pragma unroll
    for (int ni=0; ni<2; ni++) {
      int col = n0 + ni*16 + lr;
      float bl = b_log[col];
      #pragma unroll
      for (int q=0; q<4; q++) {
        int row = m0 + mi*16 + orow + q;
        float v = acc[mi][ni][q] + bl;
        out[(size_t)row*32050 + col] = (v == 0.0f) ? -INF_F : v;
      }
    }
}

// ---------------- OOV region fill ----------------
__global__ __launch_bounds__(256) void k_oov(float* __restrict__ out) {
  int idx = blockIdx.x*256 + threadIdx.x;
  if (idx >= 1024*50) return;
  int rr = idx/50, v = 32000 + idx%50;
  out[(size_t)rr*32050 + v] = -INF_F;
}

// ---------------- scatter-max of energies into extended logits ----------------
__global__ __launch_bounds__(128) void k_scatter(const int* __restrict__ ext_src,
    float* __restrict__ out) {
  __shared__ int tok[400];
  __shared__ float ev[400];
  int rr = blockIdx.x;          // r = t*32 + b
  int b = rr & 31;
  int tid = threadIdx.x;
  for (int s=tid; s<400; s+=128){
    tok[s] = ext_src[b*400+s];
    ev[s]  = out[OFF_E + (size_t)rr*400 + s];
  }
  __syncthreads();
  for (int s=tid; s<400; s+=128){
    int tk = tok[s];
    float m = ev[s];
    bool first = true;
    for (int s2=0; s2<400; s2++){
      if (tok[s2]==tk){
        if (s2 < s) first=false;
        m = fmaxf(m, ev[s2]);
      }
    }
    if (first && m != -INF_F){
      size_t idx = (size_t)rr*32050 + tk;
      float wv = out[idx];
      float extv = (wv == -INF_F) ? 0.0f : wv;
      float nv = extv + m;
      out[idx] = (nv == 0.0f) ? -INF_F : nv;
    }
  }
}

extern "C" void kernel_launch(void* const* d_in, const int* in_sizes, int n_in,
                              void* d_out, int out_size, void* d_ws, size_t ws_size,
                              hipStream_t stream) {
  const float* trg   = (const float*)d_in[0];
  const int*   ext   = (const int*)  d_in[1];
  const float* inits = (const float*)d_in[2];
  const float* enc   = (const float*)d_in[3];
  const int*   emask = (const int*)  d_in[4];
  const float* W_enc = (const float*)d_in[5];
  const float* b_enc = (const float*)d_in[6];
  const float* W_red = (const float*)d_in[7];
  const float* b_red = (const float*)d_in[8];
  const float* W_ih  = (const float*)d_in[9];
  const float* W_hh  = (const float*)d_in[10];
  const float* b_ih  = (const float*)d_in[11];
  const float* b_hh  = (const float*)d_in[12];
  const float* W_cat = (const float*)d_in[13];
  const float* b_cat = (const float*)d_in[14];
  const float* W_log = (const float*)d_in[15];
  const float* b_log = (const float*)d_in[16];
  float* out = (float*)d_out;
  float* ws  = (float*)d_ws;

  float* mem   = ws + 0ull;          // 6,553,600
  float* memT  = ws + 6553600ull;    // 6,553,600
  float* Wg    = ws + 13107200ull;   // 2,097,152
  float* Wct   = ws + 15204352ull;   // 1,662,976
  float* Gemb  = ws + 16867328ull;   // 2,097,152
  float* bcomb = ws + 18964480ull;   // 2,048
  float* hbuf  = ws + 18966528ull;   // 16,384
  float* c0    = ws + 18982912ull;   // 16,384
  float* c1    = ws + 18999296ull;   // 16,384
  float* ctxb  = ws + 19015680ull;   // 16,384
  float* hall  = ws + 19032064ull;   // 524,288
  float* ctxa  = ws + 19556352ull;   // 524,288
  float* cov   = ws + 20080640ull;   // 12,800
  float* part  = ws + 20093440ull;   // 524,288
  __hip_bfloat16* lib = (__hip_bfloat16*)(ws + 20617728ull);  // 262,144 floats
  __hip_bfloat16* wlb = (__hip_bfloat16*)(ws + 20879872ull);  // 8,192,000 floats

  k_init<<<64,256,0,stream>>>(inits, hbuf, c0, ctxb, cov);
  k_bcombo<<<8,256,0,stream>>>(W_ih, b_red, b_ih, b_hh, bcomb);
  k_wcombo<<<dim3(13,32),256,0,stream>>>(W_ih, W_red, Wct);
  k_gemb<<<dim3(32,16),256,0,stream>>>(trg, Wct, bcomb, Gemb);
  k_wgpack<<<8192,256,0,stream>>>(Wct, W_hh, Wg);
  k_memories<<<dim3(8,200),256,0,stream>>>(enc, W_enc, b_enc, mem, memT);
  k_wlogconv<<<16000,256,0,stream>>>(W_log, wlb);

  for (int t=0;t<32;t++){
    const float* c_in = (t&1) ? c1 : c0;
    float* c_out      = (t&1) ? c0 : c1;
    k_gates<<<dim3(8,16),256,0,stream>>>(ctxb, hbuf, Wg, part);
    k_lstm_energy<<<dim3(2,32),256,0,stream>>>(part, Gemb, c_in, c_out, hbuf, hall, memT, emask, out, t);
    k_ctx<<<dim3(2,32),256,0,stream>>>(out, mem, ctxb, ctxa, cov, t);
  }

  k_logitin<<<dim3(8,16),256,0,stream>>>(hall, ctxa, W_cat, b_cat, lib);
  k_logits<<<dim3(500,16),256,0,stream>>>(lib, wlb, b_log, out);
  k_oov<<<200,256,0,stream>>>(out);
  k_scatter<<<1024,128,0,stream>>>(ext, out);
}

// Round 2
// 2393.029 us; speedup vs baseline: 1.0608x; 1.0608x over previous
//
#include <hip/hip_runtime.h>
#include <hip/hip_bf16.h>

#define INF_F 1000000000000.0f

typedef __attribute__((ext_vector_type(8))) short bfrag8;
typedef __attribute__((ext_vector_type(4))) float facc4;

__device__ __forceinline__ float sigf(float x){ return 1.0f/(1.0f + expf(-x)); }

// out-region offsets (floats)
#define OFF_LOG 0ull
#define OFF_A   32819200ull
#define OFF_C   33228800ull
#define OFF_E   33638400ull

// ---------------- init ----------------
__global__ __launch_bounds__(256) void k_init(const float* __restrict__ init_s,
    float* __restrict__ hbuf, float* __restrict__ c0, float* __restrict__ ctxb,
    float* __restrict__ cov) {
  int i = blockIdx.x*256 + threadIdx.x;
  if (i < 32*512) { float v = init_s[i]; hbuf[i]=v; c0[i]=v; ctxb[i]=0.0f; }
  if (i < 32*400) cov[i] = 0.0f;
}

// ---------------- b_combo = W_ih@b_red + b_ih + b_hh ----------------
__global__ __launch_bounds__(256) void k_bcombo(const float* __restrict__ W_ih,
    const float* __restrict__ b_red, const float* __restrict__ b_ih,
    const float* __restrict__ b_hh, float* __restrict__ bcomb) {
  int j = blockIdx.x*256 + threadIdx.x;
  if (j >= 2048) return;
  float acc = b_ih[j] + b_hh[j];
  for (int m=0;m<300;m++) acc += W_ih[j*300+m]*b_red[m];
  bcomb[j] = acc;
}

// ---------------- Wct[2048][812] = W_ih[2048x300] @ W_red[300x812] ----------------
__global__ __launch_bounds__(256) void k_wcombo(const float* __restrict__ W_ih,
    const float* __restrict__ W_red, float* __restrict__ Wct) {
  __shared__ float As[16][68];
  __shared__ float Bs[16][68];
  int tid = threadIdx.x;
  int m0 = blockIdx.y*64, n0 = blockIdx.x*64;
  int rl = tid>>2, kq = (tid&3)*4;
  int kl = tid>>4, c4 = (tid&15)*4;
  int tx = tid&15, ty = tid>>4;
  float acc[4][4]={};
  for (int kk=0;kk<300;kk+=16){
    #pragma unroll
    for (int q=0;q<4;q++){
      int kg = kk+kq+q;
      As[kq+q][rl] = (kg<300) ? W_ih[(size_t)(m0+rl)*300 + kg] : 0.0f;
    }
    #pragma unroll
    for (int q=0;q<4;q++){
      int c = n0 + c4 + q;
      Bs[kl][c4+q] = (kk+kl<300 && c<812) ? W_red[(size_t)(kk+kl)*812 + c] : 0.0f;
    }
    __syncthreads();
    #pragma unroll
    for (int k=0;k<16;k++){
      const float* ap=&As[k][ty*4]; const float* bp=&Bs[k][tx*4];
      #pragma unroll
      for (int i=0;i<4;i++)
        #pragma unroll
        for (int j=0;j<4;j++) acc[i][j] += ap[i]*bp[j];
    }
    __syncthreads();
  }
  #pragma unroll
  for (int i=0;i<4;i++)
    #pragma unroll
    for (int j=0;j<4;j++){
      int row = m0+ty*4+i, col = n0+tx*4+j;
      if (col<812) Wct[(size_t)row*812 + col] = acc[i][j];
    }
}

// ---------------- G_emb[1024][2048] = emb[1024x300] @ Wct[:,0:300]^T + b_combo --------
__global__ __launch_bounds__(256) void k_gemb(const float* __restrict__ trg,
    const float* __restrict__ Wct, const float* __restrict__ bcomb,
    float* __restrict__ Gemb) {
  __shared__ float As[16][68];
  __shared__ float Bs[16][68];
  int tid = threadIdx.x;
  int m0 = blockIdx.y*64, n0 = blockIdx.x*64;
  int rl = tid>>2, kq = (tid&3)*4;
  int tx = tid&15, ty = tid>>4;
  float acc[4][4]={};
  int r = m0 + rl;
  const float* arow = trg + (size_t)(r&31)*9600 + (size_t)(r>>5)*300;
  for (int kk=0;kk<300;kk+=16){
    #pragma unroll
    for (int q=0;q<4;q++){
      int kg = kk+kq+q;
      As[kq+q][rl] = (kg<300) ? arow[kg] : 0.0f;
      Bs[kq+q][rl] = (kg<300) ? Wct[(size_t)(n0+rl)*812 + kg] : 0.0f;
    }
    __syncthreads();
    #pragma unroll
    for (int k=0;k<16;k++){
      const float* ap=&As[k][ty*4]; const float* bp=&Bs[k][tx*4];
      #pragma unroll
      for (int i=0;i<4;i++)
        #pragma unroll
        for (int j=0;j<4;j++) acc[i][j] += ap[i]*bp[j];
    }
    __syncthreads();
  }
  #pragma unroll
  for (int i=0;i<4;i++)
    #pragma unroll
    for (int j=0;j<4;j++){
      int rr = m0+ty*4+i, col = n0+tx*4+j;
      Gemb[(size_t)rr*2048 + col] = acc[i][j] + bcomb[col];
    }
}

// ---------------- Wg[1024][2048]: k<512 -> Wct[:,300+k]^T ; k>=512 -> W_hh^T ----------
__global__ __launch_bounds__(256) void k_wgpack(const float* __restrict__ Wct,
    const float* __restrict__ W_hh, float* __restrict__ Wg) {
  int idx = blockIdx.x*256 + threadIdx.x;
  if (idx >= 1024*2048) return;
  int k = idx >> 11, j = idx & 2047;
  Wg[idx] = (k < 512) ? Wct[(size_t)j*812 + 300 + k] : W_hh[(size_t)j*512 + (k-512)];
}

// ---------------- memories = enc @ W_enc^T + b_enc (dual layout) ----------------
__global__ __launch_bounds__(256) void k_memories(const float* __restrict__ A,
    const float* __restrict__ Bw, const float* __restrict__ bias,
    float* __restrict__ mem, float* __restrict__ memT) {
  __shared__ float As[16][68];
  __shared__ float Bs[16][68];
  int tid = threadIdx.x;
  int m0 = blockIdx.y*64, n0 = blockIdx.x*64;
  int rl = tid>>2, kq = (tid&3)*4;
  int tx = tid&15, ty = tid>>4;
  float acc[4][4]={};
  for (int kk=0;kk<512;kk+=16){
    float4 av = *(const float4*)(A  + (size_t)(m0+rl)*512 + kk+kq);
    float4 bv = *(const float4*)(Bw + (size_t)(n0+rl)*512 + kk+kq);
    As[kq+0][rl]=av.x; As[kq+1][rl]=av.y; As[kq+2][rl]=av.z; As[kq+3][rl]=av.w;
    Bs[kq+0][rl]=bv.x; Bs[kq+1][rl]=bv.y; Bs[kq+2][rl]=bv.z; Bs[kq+3][rl]=bv.w;
    __syncthreads();
    #pragma unroll
    for (int k=0;k<16;k++){
      const float* ap=&As[k][ty*4]; const float* bp=&Bs[k][tx*4];
      #pragma unroll
      for (int i=0;i<4;i++)
        #pragma unroll
        for (int j=0;j<4;j++) acc[i][j] += ap[i]*bp[j];
    }
    __syncthreads();
  }
  #pragma unroll
  for (int i=0;i<4;i++){
    int n = m0+ty*4+i;
    int bb = n/400, s = n - bb*400;
    #pragma unroll
    for (int j=0;j<4;j++){
      int h = n0+tx*4+j;
      float v = acc[i][j] + bias[h];
      mem[(size_t)n*512 + h] = v;
      memT[((size_t)bb*512 + h)*400 + s] = v;
    }
  }
}

// ---------------- W_log -> bf16 ----------------
__global__ __launch_bounds__(256) void k_wlogconv(const float* __restrict__ W_log,
    __hip_bfloat16* __restrict__ wlb) {
  int i4 = blockIdx.x*256 + threadIdx.x;
  if (i4 >= 32000*512/4) return;
  const float4 v = *(const float4*)(W_log + (size_t)i4*4);
  size_t o = (size_t)i4*4;
  wlb[o+0] = __float2bfloat16(v.x); wlb[o+1] = __float2bfloat16(v.y);
  wlb[o+2] = __float2bfloat16(v.z); wlb[o+3] = __float2bfloat16(v.w);
}

// ---------------- per-step: gates partial GEMM ----------------
// grid (ks=8, rc=16); partial[ks][b][row] = sum_{k in ks chunk} yh[b][k]*Wg[k][row]
__global__ __launch_bounds__(256) void k_gates(const float* __restrict__ ctxb,
    const float* __restrict__ hbuf, const float* __restrict__ Wg,
    float* __restrict__ partials) {
  __shared__ float yh_s[128][32];
  int ks = blockIdx.x;
  int rc = blockIdx.y;
  int tid = threadIdx.x;
  const float* side = (ks < 4) ? ctxb : hbuf;
  int kbase = (ks & 3) * 128;
  {
    int b_l = tid >> 3, kq0 = (tid & 7) * 16;
    const float* src = side + (size_t)b_l*512 + kbase + kq0;
    #pragma unroll
    for (int q=0;q<16;q+=4){
      float4 v = *(const float4*)(src + q);
      yh_s[kq0+q+0][b_l]=v.x; yh_s[kq0+q+1][b_l]=v.y;
      yh_s[kq0+q+2][b_l]=v.z; yh_s[kq0+q+3][b_l]=v.w;
    }
  }
  __syncthreads();
  int tr = tid & 31, bg = tid >> 5;
  int row0 = rc*128 + tr*4;
  float acc[4][4] = {};
  const float* wp = Wg + (size_t)(ks*128)*2048 + row0;
  #pragma unroll 8
  for (int k=0;k<128;k++){
    float4 w = *(const float4*)(wp + (size_t)k*2048);
    float4 y = *(const float4*)&yh_s[k][bg*4];
    acc[0][0]+=w.x*y.x; acc[0][1]+=w.x*y.y; acc[0][2]+=w.x*y.z; acc[0][3]+=w.x*y.w;
    acc[1][0]+=w.y*y.x; acc[1][1]+=w.y*y.y; acc[1][2]+=w.y*y.z; acc[1][3]+=w.y*y.w;
    acc[2][0]+=w.z*y.x; acc[2][1]+=w.z*y.y; acc[2][2]+=w.z*y.z; acc[2][3]+=w.z*y.w;
    acc[3][0]+=w.w*y.x; acc[3][1]+=w.w*y.y; acc[3][2]+=w.w*y.z; acc[3][3]+=w.w*y.w;
  }
  #pragma unroll
  for (int j=0;j<4;j++){
    float4 o; o.x=acc[0][j]; o.y=acc[1][j]; o.z=acc[2][j]; o.w=acc[3][j];
    *(float4*)(partials + (size_t)(ks*32 + bg*4 + j)*2048 + row0) = o;
  }
}

// ---------------- per-step fused: reduce+LSTM+energy+softmax+ctx ----------------
// grid: 32 blocks (one per b), 512 threads
__global__ __launch_bounds__(512) void k_step(const float* __restrict__ partials,
    const float* __restrict__ Gemb, const float* __restrict__ c_in, float* __restrict__ c_out,
    float* __restrict__ hbuf, float* __restrict__ hall,
    const float* __restrict__ memT, const float* __restrict__ mem,
    const int* __restrict__ emask, float* __restrict__ out,
    float* __restrict__ ctxb, float* __restrict__ ctxa, float* __restrict__ cov, int t) {
  __shared__ float hl[512];
  __shared__ float ps[400];
  __shared__ float redm[8];
  __shared__ float reds[8];
  int b = blockIdx.x, tid = threadIdx.x;
  int r = t*32 + b;
  int lane = tid & 63, w = tid >> 6;

  // phase 1: gate reduce + LSTM (thread = hidden unit j)
  {
    int j = tid;
    const float* gp = Gemb + (size_t)r*2048;
    float g0 = gp[j], g1 = gp[512+j], g2 = gp[1024+j], g3 = gp[1536+j];
    #pragma unroll
    for (int ks=0;ks<8;ks++){
      const float* pp = partials + (size_t)(ks*32+b)*2048;
      g0 += pp[j]; g1 += pp[512+j]; g2 += pp[1024+j]; g3 += pp[1536+j];
    }
    float cp = c_in[b*512+j];
    float cn = sigf(g1)*cp + sigf(g0)*tanhf(g2);
    float hn = sigf(g3)*tanhf(cn);
    hl[j] = hn;
    c_out[b*512+j] = cn;
    hbuf[b*512+j]  = hn;
    hall[(size_t)r*512+j] = hn;
  }
  __syncthreads();

  // phase 2: energy (thread = source position s)
  float e = -3.4e38f;
  if (tid < 400) {
    const float* mp = memT + (size_t)b*204800 + tid;
    float acc = 0.0f;
    #pragma unroll 8
    for (int h=0;h<512;h++) acc += hl[h]*mp[(size_t)h*400];
    e = (emask[b*400+tid]==0) ? -INF_F : acc;
    out[OFF_E + (size_t)r*400 + tid] = e;
  }

  // phase 3: softmax (block reduce via wave shuffles)
  float lm = e;
  #pragma unroll
  for (int off=32; off; off>>=1) lm = fmaxf(lm, __shfl_xor(lm, off));
  if (lane==0) redm[w] = lm;
  __syncthreads();
  float m = redm[0];
  #pragma unroll
  for (int i=1;i<8;i++) m = fmaxf(m, redm[i]);
  float pv = (tid<400) ? expf(e - m) : 0.0f;
  float sv = pv;
  #pragma unroll
  for (int off=32; off; off>>=1) sv += __shfl_xor(sv, off);
  if (lane==0) reds[w] = sv;
  __syncthreads();
  float sum = reds[0];
  #pragma unroll
  for (int i=1;i<8;i++) sum += reds[i];
  float inv = 1.0f/sum;
  if (tid < 400) {
    float a = pv*inv;
    ps[tid] = a;
    out[OFF_A + (size_t)r*400 + tid] = a;
    float cv = cov[b*400+tid];
    out[OFF_C + (size_t)r*400 + tid] = cv;
    cov[b*400+tid] = cv + a;
  }
  __syncthreads();

  // phase 4: ctx (thread = hidden unit h)
  {
    const float* mq = mem + (size_t)b*204800 + tid;
    float acc = 0.0f;
    #pragma unroll 8
    for (int s=0;s<400;s++) acc += ps[s]*mq[(size_t)s*512];
    ctxb[b*512+tid] = acc;
    ctxa[(size_t)r*512+tid] = acc;
  }
}

// ---------------- logit_in = tanh([h_all|ctx_all]@W_cat^T + b_cat) -> bf16 ----------
__global__ __launch_bounds__(256) void k_logitin(const float* __restrict__ hall,
    const float* __restrict__ ctxa, const float* __restrict__ W_cat,
    const float* __restrict__ b_cat, __hip_bfloat16* __restrict__ lib) {
  __shared__ float As[16][68];
  __shared__ float Bs[16][68];
  int tid = threadIdx.x;
  int m0 = blockIdx.y*64, n0 = blockIdx.x*64;
  int rl = tid>>2, kq = (tid&3)*4;
  int tx = tid&15, ty = tid>>4;
  float acc[4][4]={};
  for (int kk=0;kk<1024;kk+=16){
    int kg = kk+kq;
    const float* asrc = (kg<512) ? (hall + (size_t)(m0+rl)*512 + kg)
                                 : (ctxa + (size_t)(m0+rl)*512 + kg - 512);
    float4 av = *(const float4*)asrc;
    float4 bv = *(const float4*)(W_cat + (size_t)(n0+rl)*1024 + kg);
    As[kq+0][rl]=av.x; As[kq+1][rl]=av.y; As[kq+2][rl]=av.z; As[kq+3][rl]=av.w;
    Bs[kq+0][rl]=bv.x; Bs[kq+1][rl]=bv.y; Bs[kq+2][rl]=bv.z; Bs[kq+3][rl]=bv.w;
    __syncthreads();
    #pragma unroll
    for (int k=0;k<16;k++){
      const float* ap=&As[k][ty*4]; const float* bp=&Bs[k][tx*4];
      #pragma unroll
      for (int i=0;i<4;i++)
        #pragma unroll
        for (int j=0;j<4;j++) acc[i][j] += ap[i]*bp[j];
    }
    __syncthreads();
  }
  #pragma unroll
  for (int i=0;i<4;i++)
    #pragma unroll
    for (int j=0;j<4;j++){
      int rr = m0+ty*4+i, col = n0+tx*4+j;
      float v = tanhf(acc[i][j] + b_cat[col]);
      lib[(size_t)rr*512 + col] = __float2bfloat16(v);
    }
}

// swizzled LDS byte offset: row in [0,128), slot in [0,4) (16B granules of a 64B row)
__device__ __forceinline__ int lds_off(int row, int slot) {
  return (row<<6) + (((slot ^ ((row>>1)&3))&3)<<4);
}

// ---------------- logits = logit_in @ W_log^T + b_log (bf16 MFMA, 128x128 tile) -------
// grid (8 m-blocks, 250 n-blocks), 256 threads (4 waves 2x2)
__global__ __launch_bounds__(256) void k_logits(const __hip_bfloat16* __restrict__ Ab,
    const __hip_bfloat16* __restrict__ Wb, const float* __restrict__ b_log,
    float* __restrict__ out) {
  __shared__ short As[4096];   // 8 KB: 128 rows x 32 k (swizzled 16B granules)
  __shared__ short Bs[4096];
  int tid = threadIdx.x;
  int m0 = blockIdx.x*128, n0 = blockIdx.y*128;
  int w = tid>>6, lane = tid&63;
  int wr = w>>1, wc = w&1;
  int lr = lane&15, kg2 = lane>>4;
  const short* A = (const short*)Ab;
  const short* W = (const short*)Wb;

  int srow = tid>>1;            // 0..127
  int ss   = (tid&1)*2;         // staging slots {ss, ss+1}
  const short* ga = A + (size_t)(m0+srow)*512 + ss*8;
  const short* gw = W + (size_t)(n0+srow)*512 + ss*8;
  int wo0 = lds_off(srow, ss), wo1 = lds_off(srow, ss+1);

  int raoff[4], rboff[4];
  #pragma unroll
  for (int q=0;q<4;q++){
    raoff[q] = lds_off(wr*64 + q*16 + lr, kg2);
    rboff[q] = lds_off(wc*64 + q*16 + lr, kg2);
  }

  facc4 acc[4][4] = {};
  bfrag8 ra0 = *(const bfrag8*)(ga);
  bfrag8 ra1 = *(const bfrag8*)(ga+8);
  bfrag8 rb0 = *(const bfrag8*)(gw);
  bfrag8 rb1 = *(const bfrag8*)(gw+8);

  for (int i=0;i<16;i++){
    __syncthreads();
    *(bfrag8*)((char*)As + wo0) = ra0;
    *(bfrag8*)((char*)As + wo1) = ra1;
    *(bfrag8*)((char*)Bs + wo0) = rb0;
    *(bfrag8*)((char*)Bs + wo1) = rb1;
    __syncthreads();
    if (i<15){
      ga += 32; gw += 32;
      ra0 = *(const bfrag8*)(ga);
      ra1 = *(const bfrag8*)(ga+8);
      rb0 = *(const bfrag8*)(gw);
      rb1 = *(const bfrag8*)(gw+8);
    }
    bfrag8 af[4], bf[4];
    #pragma unroll
    for (int q=0;q<4;q++){
      af[q] = *(const bfrag8*)((char*)As + raoff[q]);
      bf[q] = *(const bfrag8*)((char*)Bs + rboff[q]);
    }
    #pragma unroll
    for (int mi=0;mi<4;mi++)
      #pragma unroll
      for (int ni=0;ni<4;ni++)
        acc[mi][ni] = __builtin_amdgcn_mfma_f32_16x16x32_bf16(af[mi], bf[ni], acc[mi][ni], 0,0,0);
  }

  #pragma unroll
  for (int mi=0;mi<4;mi++){
    int row = m0 + wr*64 + mi*16 + kg2*4;
    #pragma unroll
    for (int ni=0;ni<4;ni++){
      int col = n0 + wc*64 + ni*16 + lr;
      float bl = b_log[col];
      #pragma unroll
      for (int q=0;q<4;q++){
        float v = acc[mi][ni][q] + bl;
        out[(size_t)(row+q)*32050 + col] = (v == 0.0f) ? -INF_F : v;
      }
    }
  }
}

// ---------------- OOV region fill ----------------
__global__ __launch_bounds__(256) void k_oov(float* __restrict__ out) {
  int idx = blockIdx.x*256 + threadIdx.x;
  if (idx >= 1024*50) return;
  int rr = idx/50, v = 32000 + idx%50;
  out[(size_t)rr*32050 + v] = -INF_F;
}

// ---------------- scatter-max of energies into extended logits ----------------
__global__ __launch_bounds__(128) void k_scatter(const int* __restrict__ ext_src,
    float* __restrict__ out) {
  __shared__ int tok[400];
  __shared__ float ev[400];
  int rr = blockIdx.x;          // r = t*32 + b
  int b = rr & 31;
  int tid = threadIdx.x;
  for (int s=tid; s<400; s+=128){
    tok[s] = ext_src[b*400+s];
    ev[s]  = out[OFF_E + (size_t)rr*400 + s];
  }
  __syncthreads();
  for (int s=tid; s<400; s+=128){
    int tk = tok[s];
    float m = ev[s];
    bool first = true;
    for (int s2=0; s2<400; s2++){
      if (tok[s2]==tk){
        if (s2 < s) first=false;
        m = fmaxf(m, ev[s2]);
      }
    }
    if (first && m != -INF_F){
      size_t idx = (size_t)rr*32050 + tk;
      float wv = out[idx];
      float extv = (wv == -INF_F) ? 0.0f : wv;
      float nv = extv + m;
      out[idx] = (nv == 0.0f) ? -INF_F : nv;
    }
  }
}

extern "C" void kernel_launch(void* const* d_in, const int* in_sizes, int n_in,
                              void* d_out, int out_size, void* d_ws, size_t ws_size,
                              hipStream_t stream) {
  const float* trg   = (const float*)d_in[0];
  const int*   ext   = (const int*)  d_in[1];
  const float* inits = (const float*)d_in[2];
  const float* enc   = (const float*)d_in[3];
  const int*   emask = (const int*)  d_in[4];
  const float* W_enc = (const float*)d_in[5];
  const float* b_enc = (const float*)d_in[6];
  const float* W_red = (const float*)d_in[7];
  const float* b_red = (const float*)d_in[8];
  const float* W_ih  = (const float*)d_in[9];
  const float* W_hh  = (const float*)d_in[10];
  const float* b_ih  = (const float*)d_in[11];
  const float* b_hh  = (const float*)d_in[12];
  const float* W_cat = (const float*)d_in[13];
  const float* b_cat = (const float*)d_in[14];
  const float* W_log = (const float*)d_in[15];
  const float* b_log = (const float*)d_in[16];
  float* out = (float*)d_out;
  float* ws  = (float*)d_ws;

  float* mem   = ws + 0ull;          // 6,553,600
  float* memT  = ws + 6553600ull;    // 6,553,600
  float* Wg    = ws + 13107200ull;   // 2,097,152
  float* Wct   = ws + 15204352ull;   // 1,662,976
  float* Gemb  = ws + 16867328ull;   // 2,097,152
  float* bcomb = ws + 18964480ull;   // 2,048
  float* hbuf  = ws + 18966528ull;   // 16,384
  float* c0    = ws + 18982912ull;   // 16,384
  float* c1    = ws + 18999296ull;   // 16,384
  float* ctxb  = ws + 19015680ull;   // 16,384
  float* hall  = ws + 19032064ull;   // 524,288
  float* ctxa  = ws + 19556352ull;   // 524,288
  float* cov   = ws + 20080640ull;   // 12,800
  float* part  = ws + 20093440ull;   // 524,288
  __hip_bfloat16* lib = (__hip_bfloat16*)(ws + 20617728ull);  // 262,144 floats
  __hip_bfloat16* wlb = (__hip_bfloat16*)(ws + 20879872ull);  // 8,192,000 floats

  k_init<<<64,256,0,stream>>>(inits, hbuf, c0, ctxb, cov);
  k_bcombo<<<8,256,0,stream>>>(W_ih, b_red, b_ih, b_hh, bcomb);
  k_wcombo<<<dim3(13,32),256,0,stream>>>(W_ih, W_red, Wct);
  k_gemb<<<dim3(32,16),256,0,stream>>>(trg, Wct, bcomb, Gemb);
  k_wgpack<<<8192,256,0,stream>>>(Wct, W_hh, Wg);
  k_memories<<<dim3(8,200),256,0,stream>>>(enc, W_enc, b_enc, mem, memT);
  k_wlogconv<<<16000,256,0,stream>>>(W_log, wlb);

  for (int t=0;t<32;t++){
    const float* c_in = (t&1) ? c1 : c0;
    float* c_out      = (t&1) ? c0 : c1;
    k_gates<<<dim3(8,16),256,0,stream>>>(ctxb, hbuf, Wg, part);
    k_step<<<32,512,0,stream>>>(part, Gemb, c_in, c_out, hbuf, hall, memT, mem,
                                emask, out, ctxb, ctxa, cov, t);
  }

  k_logitin<<<dim3(8,16),256,0,stream>>>(hall, ctxa, W_cat, b_cat, lib);
  k_logits<<<dim3(8,250),256,0,stream>>>(lib, wlb, b_log, out);
  k_oov<<<200,256,0,stream>>>(out);
  k_scatter<<<1024,128,0,stream>>>(ext, out);
}